// Round 6
// baseline (145.527 us; speedup 1.0000x reference)
//
#include <hip/hip_runtime.h>

#define B_  512
#define T_  365
#define C_  10
#define P_  64
#define K_  3650   // T*C
#define K2_ 1825   // K_ in float2

// d_out flat offsets (floats), in reference return order
#define OFF_OUT0 0u          // output_seq [B,T,C]
#define OFF_IN   1868800u    // input_seq  [B,T,C]
#define OFF_DIST 3737600u    // distances  [B,P]
#define OFF_IDX  3770368u    // indices    [B]
#define OFF_LAB  3770880u    // label      [B]
#define OFF_MASK 3771392u    // mask       [B,T]

// Grid: 256 blocks = 64 batch-groups (8 rows) x 4 proto-quarters (16 protos).
// 512 threads = 8 waves; wave w owns protos p0+2w, p0+2w+1 over full K.
// Dot-form: d[b][p] = x2m[b] - 2*sum_k m*x*p + sum_k m*p^2, with m per
// element = mrow[t], t = k/10. Float2 pairs never straddle a t boundary
// (boundaries at even k). x rows re-read by all 8 waves -> L2-resident
// (117 KB block working set); protos read once per block -> 60 MB L3 total
// vs 239 MB in the previous round. No big LDS: accumulators in registers.
__global__ __launch_bounds__(512, 4) void dist_kernel(
    const float* __restrict__ x, const float* __restrict__ mask,
    const float* __restrict__ protos, float* __restrict__ out)
{
    __shared__ float mrow[8][372];   // mask rows (t<365 valid, rest zero)
    __shared__ float x2s[8];

    const int tid  = threadIdx.x;
    const int lane = tid & 63;
    const int wv   = tid >> 6;           // 0..7
    const int g    = blockIdx.x >> 2;    // batch group
    const int q    = blockIdx.x & 3;     // proto quarter
    const int b0   = g * 8;
    const int p0   = q * 16;

    // ---- stage mask rows (+ mask echo from quarter-0 blocks) ----
#pragma unroll
    for (int r = 0; r < 8; ++r) {
        if (tid < 372) {
            float m = (tid < T_) ? mask[(size_t)(b0 + r) * T_ + tid] : 0.f;
            mrow[r][tid] = m;
            if (q == 0 && tid < T_)
                out[OFF_MASK + (size_t)(b0 + r) * T_ + tid] = m;
        }
    }
    __syncthreads();

    // ---- pointers (wave-uniform bases -> SGPRs) ----
    const int pidx = p0 + wv * 2;
    const float2* pr0 = (const float2*)(protos + (size_t)pidx * K_);
    const float2* pr1 = (const float2*)(protos + (size_t)(pidx + 1) * K_);
    const float2* xr[8];
    float2*       er[8];
#pragma unroll
    for (int r = 0; r < 8; ++r) {
        xr[r] = (const float2*)(x + (size_t)(b0 + r) * K_);
        er[r] = (float2*)(out + OFF_IN + (size_t)(b0 + r) * K_);
    }
    const bool echo = (q == 0) && (wv == 0);
    const bool dox2 = (wv == 0);

    float2 a0[8], a1[8], xq[8];
    float  c0[8], c1[8];
#pragma unroll
    for (int r = 0; r < 8; ++r) {
        a0[r] = {0.f, 0.f}; a1[r] = {0.f, 0.f}; xq[r] = {0.f, 0.f};
        c0[r] = 0.f; c1[r] = 0.f;
    }

    // ---- main K-loop: 28 full iters + guarded tail ----
    for (int it = 0; it < 28; ++it) {
        const int i2 = it * 64 + lane;           // < 1792 < 1825
        const unsigned t = (unsigned)i2 / 5u;    // element t index (<=358)
        const float2 pv0 = pr0[i2];
        const float2 pv1 = pr1[i2];
        const float s0 = fmaf(pv0.x, pv0.x, pv0.y * pv0.y);
        const float s1 = fmaf(pv1.x, pv1.x, pv1.y * pv1.y);
#pragma unroll
        for (int r = 0; r < 8; ++r) {
            const float  m  = mrow[r][t];
            const float2 xv = xr[r][i2];
            if (echo) er[r][i2] = xv;
            float2 xmv;
            xmv.x = xv.x * m;
            xmv.y = xv.y * m;
            a0[r].x = fmaf(xmv.x, pv0.x, a0[r].x);
            a0[r].y = fmaf(xmv.y, pv0.y, a0[r].y);
            a1[r].x = fmaf(xmv.x, pv1.x, a1[r].x);
            a1[r].y = fmaf(xmv.y, pv1.y, a1[r].y);
            c0[r] = fmaf(m, s0, c0[r]);
            c1[r] = fmaf(m, s1, c1[r]);
            if (dox2) {
                xq[r].x = fmaf(xmv.x, xmv.x, xq[r].x);
                xq[r].y = fmaf(xmv.y, xmv.y, xq[r].y);
            }
        }
    }
    {   // tail: i2 in [1792, 1825)
        const int i2 = 28 * 64 + lane;
        if (i2 < K2_) {
            const unsigned t = (unsigned)i2 / 5u;
            const float2 pv0 = pr0[i2];
            const float2 pv1 = pr1[i2];
            const float s0 = fmaf(pv0.x, pv0.x, pv0.y * pv0.y);
            const float s1 = fmaf(pv1.x, pv1.x, pv1.y * pv1.y);
#pragma unroll
            for (int r = 0; r < 8; ++r) {
                const float  m  = mrow[r][t];
                const float2 xv = xr[r][i2];
                if (echo) er[r][i2] = xv;
                float2 xmv;
                xmv.x = xv.x * m;
                xmv.y = xv.y * m;
                a0[r].x = fmaf(xmv.x, pv0.x, a0[r].x);
                a0[r].y = fmaf(xmv.y, pv0.y, a0[r].y);
                a1[r].x = fmaf(xmv.x, pv1.x, a1[r].x);
                a1[r].y = fmaf(xmv.y, pv1.y, a1[r].y);
                c0[r] = fmaf(m, s0, c0[r]);
                c1[r] = fmaf(m, s1, c1[r]);
                if (dox2) {
                    xq[r].x = fmaf(xmv.x, xmv.x, xq[r].x);
                    xq[r].y = fmaf(xmv.y, xmv.y, xq[r].y);
                }
            }
        }
    }

    // ---- x2m: wave 0 reduces and publishes ----
    if (dox2) {
#pragma unroll
        for (int r = 0; r < 8; ++r) {
            float v = xq[r].x + xq[r].y;
            for (int off = 32; off; off >>= 1) v += __shfl_down(v, off);
            if (lane == 0) x2s[r] = v;
        }
    }
    __syncthreads();

    // ---- combine + wave reductions + write distances ----
#pragma unroll
    for (int r = 0; r < 8; ++r) {
        float v0 = fmaf(-2.f, a0[r].x + a0[r].y, c0[r]);
        float v1 = fmaf(-2.f, a1[r].x + a1[r].y, c1[r]);
        for (int off = 32; off; off >>= 1) {
            v0 += __shfl_down(v0, off);
            v1 += __shfl_down(v1, off);
        }
        if (lane == 0) {
            const float base = x2s[r];
            out[OFF_DIST + (size_t)(b0 + r) * P_ + pidx]     = base + v0;
            out[OFF_DIST + (size_t)(b0 + r) * P_ + pidx + 1] = base + v1;
        }
    }
}

// One block per sample: argmin over 64 distances (first-occurrence
// tie-break), idx/label echo, gather selected proto row.
__global__ __launch_bounds__(256) void argmin_kernel(
    const int* __restrict__ label, const float* __restrict__ protos,
    float* __restrict__ out)
{
    __shared__ int sel;
    const int b    = blockIdx.x;
    const int tid  = threadIdx.x;
    const int lane = tid & 63;

    if (tid < 64) {
        float v = out[OFF_DIST + (size_t)b * P_ + lane];
        int idx = lane;
        for (int off = 32; off; off >>= 1) {
            float ov = __shfl_down(v, off);
            int   oi = __shfl_down(idx, off);
            if (ov < v || (ov == v && oi < idx)) { v = ov; idx = oi; }
        }
        if (lane == 0) {
            sel = idx;
            out[OFF_IDX + b] = (float)idx;
            out[OFF_LAB + b] = (float)label[b];
        }
    }
    __syncthreads();

    const float2* src = (const float2*)(protos + (size_t)sel * K_);
    float2* dst = (float2*)(out + OFF_OUT0 + (size_t)b * K_);
    for (int i2 = tid; i2 < K2_; i2 += 256) dst[i2] = src[i2];
}

extern "C" void kernel_launch(void* const* d_in, const int* in_sizes, int n_in,
                              void* d_out, int out_size, void* d_ws, size_t ws_size,
                              hipStream_t stream) {
    const float* x      = (const float*)d_in[0];
    const float* mask   = (const float*)d_in[1];
    const int*   label  = (const int*)d_in[2];
    const float* protos = (const float*)d_in[3];
    float* out = (float*)d_out;

    dist_kernel<<<256, 512, 0, stream>>>(x, mask, protos, out);
    argmin_kernel<<<B_, 256, 0, stream>>>(label, protos, out);
}

// Round 7
// 91.728 us; speedup vs baseline: 1.5865x; 1.5865x over previous
//
#include <hip/hip_runtime.h>

#define B_   512
#define T_   365
#define C_   10
#define P_   64
#define K_   3650   // T*C
#define K2_  1825   // K_ in float2
#define KP2_ 1856   // padded float2 count (29*64)
#define TP_  372    // padded mask row (t max = 1855/5 = 371)

// d_out flat offsets (floats), in reference return order
#define OFF_OUT0 0u          // output_seq [B,T,C]
#define OFF_IN   1868800u    // input_seq  [B,T,C]
#define OFF_DIST 3737600u    // distances  [B,P]
#define OFF_IDX  3770368u    // indices    [B]
#define OFF_LAB  3770880u    // label      [B]
#define OFF_MASK 3771392u    // mask       [B,T]

// Grid: 256 blocks = 128 batch-groups (4 rows) x 2 proto-halves (32 protos).
// 1024 threads = 16 waves; wave w owns protos h*32+2w, h*32+2w+1 over 4 rows.
// h = blockIdx&1 and XCD = blockIdx%8 => each XCD reads only one 467 KB proto
// half -> L2-resident. Within a block each proto byte is read exactly once
// (120 MB total L2 traffic vs 239 MB before).
// Dot-form: d'[b][p] = -2*sum_k xm*p + sum_k m*p^2  (x2m added by kernel 2).
// float2 pairs never straddle a t boundary (t = i2/5). LDS xm zero-padded,
// mrow zero-padded to t=371, proto index clamped -> padded lanes contribute 0.
__global__ __launch_bounds__(1024, 4) void dist_kernel(
    const float* __restrict__ x, const float* __restrict__ mask,
    const float* __restrict__ protos, float* __restrict__ out)
{
    __shared__ float xm[4][2 * KP2_];   // masked x rows (float2-view), padded
    __shared__ float mrow[4][TP_];      // mask rows, zero tail

    const int tid  = threadIdx.x;
    const int lane = tid & 63;
    const int wv   = tid >> 6;           // 0..15
    const int h    = blockIdx.x & 1;     // proto half
    const int g    = blockIdx.x >> 1;    // batch group
    const int b0   = g * 4;

    // ---- stage mask rows (+ echo from half 0) ----
    for (int j = tid; j < 4 * TP_; j += 1024) {
        const int r = j / TP_;
        const int t = j - r * TP_;
        float m = 0.f;
        if (t < T_) {
            m = mask[(size_t)(b0 + r) * T_ + t];
            if (h == 0) out[OFF_MASK + (size_t)(b0 + r) * T_ + t] = m;
        }
        mrow[r][t] = m;
    }
    __syncthreads();

    // ---- stage masked x rows (float2) + fused input echo ----
#pragma unroll
    for (int r = 0; r < 4; ++r) {
        const float2* xr = (const float2*)(x + (size_t)(b0 + r) * K_);
        float2*       er = (float2*)(out + OFF_IN + (size_t)(b0 + r) * K_);
        float2*       sx = (float2*)&xm[r][0];
        for (int i2 = tid; i2 < KP2_; i2 += 1024) {
            float2 v = {0.f, 0.f};
            if (i2 < K2_) {
                v = xr[i2];
                if (h == 0) er[i2] = v;
                const unsigned t = (unsigned)i2 / 5u;
                const float m = mrow[r][t];
                v.x *= m;
                v.y *= m;
            }
            sx[i2] = v;
        }
    }
    __syncthreads();

    // ---- main K-loop: 2 protos x 4 rows per wave, 29 steps, unroll 4 ----
    const int pidx = h * 32 + wv * 2;
    const float2* pr0 = (const float2*)(protos + (size_t)pidx * K_);
    const float2* pr1 = (const float2*)(protos + (size_t)(pidx + 1) * K_);

    float2 a0[4], a1[4];
    float  c0[4], c1[4];
#pragma unroll
    for (int r = 0; r < 4; ++r) {
        a0[r] = {0.f, 0.f}; a1[r] = {0.f, 0.f};
        c0[r] = 0.f; c1[r] = 0.f;
    }

#pragma unroll 4
    for (int it = 0; it < 29; ++it) {
        const int i2  = it * 64 + lane;             // < 1856 (LDS padded)
        const int i2c = i2 < K2_ ? i2 : (K2_ - 1);  // clamp proto load only
        const unsigned t = (unsigned)i2 / 5u;       // <= 371, mrow padded
        const float2 pv0 = pr0[i2c];
        const float2 pv1 = pr1[i2c];
        const float s0 = fmaf(pv0.x, pv0.x, pv0.y * pv0.y);
        const float s1 = fmaf(pv1.x, pv1.x, pv1.y * pv1.y);
#pragma unroll
        for (int r = 0; r < 4; ++r) {
            const float2 u = ((const float2*)&xm[r][0])[i2];
            const float  m = mrow[r][t];
            a0[r].x = fmaf(u.x, pv0.x, a0[r].x);
            a0[r].y = fmaf(u.y, pv0.y, a0[r].y);
            a1[r].x = fmaf(u.x, pv1.x, a1[r].x);
            a1[r].y = fmaf(u.y, pv1.y, a1[r].y);
            c0[r] = fmaf(m, s0, c0[r]);
            c1[r] = fmaf(m, s1, c1[r]);
        }
    }

    // ---- reduce, write partial distances d' (x2m added by kernel 2) ----
#pragma unroll
    for (int r = 0; r < 4; ++r) {
        float v0 = fmaf(-2.f, a0[r].x + a0[r].y, c0[r]);
        float v1 = fmaf(-2.f, a1[r].x + a1[r].y, c1[r]);
        for (int off = 32; off; off >>= 1) {
            v0 += __shfl_down(v0, off);
            v1 += __shfl_down(v1, off);
        }
        if (lane == 0) {
            out[OFF_DIST + (size_t)(b0 + r) * P_ + pidx]     = v0;
            out[OFF_DIST + (size_t)(b0 + r) * P_ + pidx + 1] = v1;
        }
    }
}

// One block per sample: compute x2m, finalize distances (+x2m), argmin
// (first-occurrence tie-break), idx/label echo, gather selected proto row.
__global__ __launch_bounds__(256) void argmin_kernel(
    const float* __restrict__ x, const float* __restrict__ mask,
    const int* __restrict__ label, const float* __restrict__ protos,
    float* __restrict__ out)
{
    __shared__ float red[4];
    __shared__ float x2sh;
    __shared__ int   sel;

    const int b    = blockIdx.x;
    const int tid  = threadIdx.x;
    const int lane = tid & 63;
    const int wv   = tid >> 6;

    // x2m = sum_k m * x^2
    const float2* xr = (const float2*)(x + (size_t)b * K_);
    const float*  mr = mask + (size_t)b * T_;
    float s = 0.f;
    for (int i2 = tid; i2 < K2_; i2 += 256) {
        const float2 v = xr[i2];
        const float  m = mr[(unsigned)i2 / 5u];
        s = fmaf(m, fmaf(v.x, v.x, v.y * v.y), s);
    }
    for (int off = 32; off; off >>= 1) s += __shfl_down(s, off);
    if (lane == 0) red[wv] = s;
    __syncthreads();
    if (tid == 0) x2sh = red[0] + red[1] + red[2] + red[3];
    __syncthreads();

    // finalize distances + argmin
    if (tid < 64) {
        const float x2 = x2sh;
        float v = out[OFF_DIST + (size_t)b * P_ + tid] + x2;
        out[OFF_DIST + (size_t)b * P_ + tid] = v;
        int idx = tid;
        for (int off = 32; off; off >>= 1) {
            float ov = __shfl_down(v, off);
            int   oi = __shfl_down(idx, off);
            if (ov < v || (ov == v && oi < idx)) { v = ov; idx = oi; }
        }
        if (tid == 0) {
            sel = idx;
            out[OFF_IDX + b] = (float)idx;
            out[OFF_LAB + b] = (float)label[b];
        }
    }
    __syncthreads();

    // gather selected prototype row into output_seq
    const float2* src = (const float2*)(protos + (size_t)sel * K_);
    float2* dst = (float2*)(out + OFF_OUT0 + (size_t)b * K_);
    for (int i2 = tid; i2 < K2_; i2 += 256) dst[i2] = src[i2];
}

extern "C" void kernel_launch(void* const* d_in, const int* in_sizes, int n_in,
                              void* d_out, int out_size, void* d_ws, size_t ws_size,
                              hipStream_t stream) {
    const float* x      = (const float*)d_in[0];
    const float* mask   = (const float*)d_in[1];
    const int*   label  = (const int*)d_in[2];
    const float* protos = (const float*)d_in[3];
    float* out = (float*)d_out;

    dist_kernel<<<256, 1024, 0, stream>>>(x, mask, protos, out);
    argmin_kernel<<<B_, 256, 0, stream>>>(x, mask, label, protos, out);
}